// Round 2
// baseline (1043.140 us; speedup 1.0000x reference)
//
#include <hip/hip_runtime.h>
#include <stdint.h>

#define B_ 4
#define SQ_ 1024
#define SKV_ 2048
#define D_ 1024
#define H_ 16
#define HD_ 64

typedef short v8s __attribute__((ext_vector_type(8)));
typedef float v4f __attribute__((ext_vector_type(4)));

static __device__ __forceinline__ unsigned short f2bf(float f) {
  union { float f; unsigned int u; } c; c.f = f;
  unsigned int u = c.u;
  return (unsigned short)((u + 0x7fffu + ((u >> 16) & 1u)) >> 16);
}

static __device__ __forceinline__ void gll16(const void* g, void* l) {
  __builtin_amdgcn_global_load_lds((__attribute__((address_space(1))) void*)g,
                                   (__attribute__((address_space(3))) void*)l,
                                   16, 0, 0);
}

#define LGKM0() do { asm volatile("s_waitcnt lgkmcnt(0)" ::: "memory"); \
                     __builtin_amdgcn_sched_barrier(0); } while (0)

// ---------------- fp32 -> bf16 elementwise convert ----------------
__global__ void f2bf_k(const float* __restrict__ in, unsigned short* __restrict__ out, int n4) {
  int i = blockIdx.x * 256 + threadIdx.x;
  if (i < n4) {
    const float4 v = ((const float4*)in)[i];
    ushort4 o;
    o.x = f2bf(v.x); o.y = f2bf(v.y); o.z = f2bf(v.z); o.w = f2bf(v.w);
    ((ushort4*)out)[i] = o;
  }
}

// ---------------- transpose-convert: W[K][N] fp32 -> Wt[N][K] bf16 ----------------
__global__ void tconv_k(const float* __restrict__ W, unsigned short* __restrict__ Wt, int K, int N) {
  __shared__ float t[32][33];
  const int n0 = blockIdx.x * 32, k0 = blockIdx.y * 32;
  const int tx = threadIdx.x, ty = threadIdx.y;  // 32 x 8
#pragma unroll
  for (int r = 0; r < 32; r += 8)
    t[ty + r][tx] = W[(size_t)(k0 + ty + r) * N + (n0 + tx)];
  __syncthreads();
#pragma unroll
  for (int r = 0; r < 32; r += 8)
    Wt[(size_t)(n0 + ty + r) * K + (k0 + tx)] = f2bf(t[tx][ty + r]);
}

// ---------------- bf16 GEMM: C = A(MxK) * Bt(NxK)^T + bias ----------------
// BK=64, XOR-swizzled LDS (pre-swizzled global source + swizzled frag reads).
// EPI 0: bf16 Q (b,h,sq,hd).  EPI 1: bf16 K (b,h,skv,hd) | Vt (b,h,hd,skv).
// EPI 2: fp32 row-major MxN.
template <int EPI>
__global__ __launch_bounds__(256)
void gemm_bt(const unsigned short* __restrict__ A,
             const unsigned short* __restrict__ Bt,
             const float* __restrict__ bias,
             unsigned short* __restrict__ O0,
             unsigned short* __restrict__ O1,
             float* __restrict__ OF,
             int M, int N, int K) {
  __shared__ __align__(16) char smem[32768];
  unsigned short* As = (unsigned short*)smem;          // [128][64] bf16, 16KB
  unsigned short* Bs = (unsigned short*)(smem + 16384);

  const int tid = threadIdx.x;
  const int lane = tid & 63;
  const int w = tid >> 6;
  const int wm = w >> 1, wn = w & 1;
  const int l15 = lane & 15, l4 = lane >> 4;
  const int m0 = blockIdx.x * 128;
  const int n0 = blockIdx.y * 128;

  v4f acc[4][4];
#pragma unroll
  for (int i = 0; i < 4; i++)
#pragma unroll
    for (int j = 0; j < 4; j++) acc[i][j] = (v4f){0.f, 0.f, 0.f, 0.f};

  const int sr = tid >> 3;                 // staging row 0..31 (per 32-row round)
  const int sg = tid & 7;                  // 16B granule in 128B row
  const int scol = (sg ^ (sr & 7)) * 8;    // pre-swizzled source col (elems)
  const unsigned short* gA = A + (size_t)(m0 + sr) * K + scol;
  const unsigned short* gB = Bt + (size_t)(n0 + sr) * K + scol;
  char* lA = (char*)As + tid * 16;
  char* lB = (char*)Bs + tid * 16;

  for (int k0 = 0; k0 < K; k0 += 64) {
    __syncthreads();
#pragma unroll
    for (int r = 0; r < 4; r++) {
      gll16(gA + (size_t)(r * 32) * K + k0, lA + r * 4096);
      gll16(gB + (size_t)(r * 32) * K + k0, lB + r * 4096);
    }
    __syncthreads();
#pragma unroll
    for (int kk = 0; kk < 2; kk++) {
      v8s af[4], bg[4];
#pragma unroll
      for (int mi = 0; mi < 4; mi++) {
        const int row = wm * 64 + mi * 16 + l15;
        af[mi] = *(const v8s*)((const char*)As + row * 128 + (((kk * 4 + l4) ^ (row & 7)) * 16));
      }
#pragma unroll
      for (int ni = 0; ni < 4; ni++) {
        const int row = wn * 64 + ni * 16 + l15;
        bg[ni] = *(const v8s*)((const char*)Bs + row * 128 + (((kk * 4 + l4) ^ (row & 7)) * 16));
      }
#pragma unroll
      for (int mi = 0; mi < 4; mi++)
#pragma unroll
        for (int ni = 0; ni < 4; ni++)
          acc[mi][ni] = __builtin_amdgcn_mfma_f32_16x16x32_bf16(af[mi], bg[ni], acc[mi][ni], 0, 0, 0);
    }
  }

  __syncthreads();  // protect As reuse as transpose buffer

  float bsel[4];
#pragma unroll
  for (int ni = 0; ni < 4; ni++) bsel[ni] = bias[n0 + wn * 64 + ni * 16 + l15];

  if (EPI == 1 && n0 >= D_) {
    // Vt half: lane's 4 j-values are consecutive skv -> packed 8B stores.
#pragma unroll
    for (int mi = 0; mi < 4; mi++) {
#pragma unroll
      for (int ni = 0; ni < 4; ni++) {
        const int n2 = n0 + wn * 64 + ni * 16 + l15 - D_;
        const int hh = n2 >> 6, hd = n2 & 63;
        const int m = m0 + wm * 64 + mi * 16 + l4 * 4;
        const int bb = m >> 11, skv = m & 2047;
        ushort4 o;
        o.x = f2bf(acc[mi][ni][0] + bsel[ni]);
        o.y = f2bf(acc[mi][ni][1] + bsel[ni]);
        o.z = f2bf(acc[mi][ni][2] + bsel[ni]);
        o.w = f2bf(acc[mi][ni][3] + bsel[ni]);
        *(ushort4*)&O1[(((size_t)(bb * H_ + hh)) * HD_ + hd) * SKV_ + skv] = o;
      }
    }
    return;
  }

  // transpose path via per-wave LDS slice [16][68] fp32 (padded: conflict-free)
  float* T = (float*)(smem + w * 4352);
#pragma unroll
  for (int mi = 0; mi < 4; mi++) {
    LGKM0();
#pragma unroll
    for (int ni = 0; ni < 4; ni++)
#pragma unroll
      for (int j = 0; j < 4; j++)
        T[(l4 * 4 + j) * 68 + ni * 16 + l15] = acc[mi][ni][j] + bsel[ni];
    LGKM0();
    const int m = m0 + wm * 64 + mi * 16 + l15;  // lane's output row
    if (EPI == 2) {
#pragma unroll
      for (int s = 0; s < 4; s++) {
        const int c = l4 * 4 + s * 16;
        *(float4*)&OF[(size_t)m * N + n0 + wn * 64 + c] = *(const float4*)&T[l15 * 68 + c];
      }
    } else {
      const int hh = (n0 + wn * 64) >> 6;
#pragma unroll
      for (int s = 0; s < 2; s++) {
        const int c = l4 * 8 + s * 32;  // hd base
        const float4 u = *(const float4*)&T[l15 * 68 + c];
        const float4 v = *(const float4*)&T[l15 * 68 + c + 4];
        ushort4 o0, o1;
        o0.x = f2bf(u.x); o0.y = f2bf(u.y); o0.z = f2bf(u.z); o0.w = f2bf(u.w);
        o1.x = f2bf(v.x); o1.y = f2bf(v.y); o1.z = f2bf(v.z); o1.w = f2bf(v.w);
        size_t base;
        if (EPI == 0) {
          const int bb = m >> 10, sq = m & 1023;
          base = (((size_t)(bb * H_ + hh)) * SQ_ + sq) * HD_ + c;
        } else {
          const int bb = m >> 11, skv = m & 2047;
          base = (((size_t)(bb * H_ + hh)) * SKV_ + skv) * HD_ + c;
        }
        ushort4* dst = (ushort4*)&O0[base];
        dst[0] = o0; dst[1] = o1;
      }
    }
  }
}

// ---------------- fused cross-attention core (barrier-free) ----------------
// grid 1024 blocks x 256 thr = 4 waves x 16 q-rows. Swapped QK^T: lane owns one
// q-row (col=l15), kvc = kf*16+l4*4+j. K/V read direct from L2 (256KB slices).
__global__ __launch_bounds__(256)
void attn_k(const unsigned short* __restrict__ Qb,
            const unsigned short* __restrict__ Kb,
            const unsigned short* __restrict__ Vtb,
            const float* __restrict__ mask,
            float* __restrict__ AW,
            unsigned short* __restrict__ X) {
  __shared__ __align__(16) unsigned short Ps[4][16 * 64];  // per-wave P buffer

  const int tid = threadIdx.x;
  const int lane = tid & 63;
  const int w = tid >> 6;
  const int l15 = lane & 15, l4 = lane >> 4;

  int id = blockIdx.x + 16 * blockIdx.y + 256 * blockIdx.z;
  id = (id & 7) * 128 + (id >> 3);          // XCD-contiguous swizzle (1024%8==0, bijective)
  const int qt = id & 15, h = (id >> 4) & 15, b = id >> 8;
  const int bh = b * H_ + h;

  const int q = qt * 64 + w * 16 + l15;     // lane's q-row
  const size_t qbase = ((size_t)bh * SQ_ + q) * HD_;
  const v8s qf0 = *(const v8s*)&Qb[qbase + l4 * 8];
  const v8s qf1 = *(const v8s*)&Qb[qbase + 32 + l4 * 8];

  const size_t kgbase = (size_t)bh * SKV_ * HD_;
  const size_t vgbase = (size_t)bh * HD_ * SKV_;
  const float* mkb = mask + (size_t)b * SKV_;

  const float c1 = 0.18033688011112042f;   // log2(e)/8
  const float c2 = 1.4426950408889634f;    // log2(e)

  float m2 = -1e30f, l2 = 0.f;

  // ---- pass 1: row max / sum in log2 domain ----
  for (int t = 0; t < SKV_ / 64; ++t) {
    const int kv0 = t * 64;
    float sv[4][4];
#pragma unroll
    for (int kf = 0; kf < 4; kf++) {
      const int kr = kv0 + kf * 16 + l15;
      const v8s a0 = *(const v8s*)&Kb[kgbase + (size_t)kr * HD_ + l4 * 8];
      const v8s a1 = *(const v8s*)&Kb[kgbase + (size_t)kr * HD_ + 32 + l4 * 8];
      v4f a = (v4f){0.f, 0.f, 0.f, 0.f};
      a = __builtin_amdgcn_mfma_f32_16x16x32_bf16(a0, qf0, a, 0, 0, 0);
      a = __builtin_amdgcn_mfma_f32_16x16x32_bf16(a1, qf1, a, 0, 0, 0);
      const float4 mk4 = *(const float4*)&mkb[kv0 + kf * 16 + l4 * 4];
      sv[kf][0] = fmaf(a[0], c1, mk4.x * c2);
      sv[kf][1] = fmaf(a[1], c1, mk4.y * c2);
      sv[kf][2] = fmaf(a[2], c1, mk4.z * c2);
      sv[kf][3] = fmaf(a[3], c1, mk4.w * c2);
    }
    float mx = sv[0][0];
#pragma unroll
    for (int kf = 0; kf < 4; kf++)
#pragma unroll
      for (int j = 0; j < 4; j++) mx = fmaxf(mx, sv[kf][j]);
    const float mn = fmaxf(m2, mx);
    float add = 0.f;
#pragma unroll
    for (int kf = 0; kf < 4; kf++)
#pragma unroll
      for (int j = 0; j < 4; j++) add += exp2f(sv[kf][j] - mn);
    l2 = l2 * exp2f(m2 - mn) + add;
    m2 = mn;
  }
  // combine across the 4 l4-groups (lanes xor 16, 32)
#pragma unroll
  for (int off = 16; off < 64; off <<= 1) {
    const float mo = __shfl_xor(m2, off);
    const float lo = __shfl_xor(l2, off);
    const float mn = fmaxf(m2, mo);
    l2 = l2 * exp2f(m2 - mn) + lo * exp2f(mo - mn);
    m2 = mn;
  }
  const float C = m2 + __log2f(l2);  // p = 2^(sv - C), no division

  v4f oa[4];
#pragma unroll
  for (int nf = 0; nf < 4; nf++) oa[nf] = (v4f){0.f, 0.f, 0.f, 0.f};

  float* awrow = AW + ((size_t)bh * SQ_ + q) * SKV_;
  unsigned short* PsW = &Ps[w][0];

  // ---- pass 2: recompute S, write AW (float4), PV via MFMA ----
  for (int t = 0; t < SKV_ / 64; ++t) {
    const int kv0 = t * 64;
#pragma unroll
    for (int kf = 0; kf < 4; kf++) {
      const int kr = kv0 + kf * 16 + l15;
      const v8s a0 = *(const v8s*)&Kb[kgbase + (size_t)kr * HD_ + l4 * 8];
      const v8s a1 = *(const v8s*)&Kb[kgbase + (size_t)kr * HD_ + 32 + l4 * 8];
      v4f a = (v4f){0.f, 0.f, 0.f, 0.f};
      a = __builtin_amdgcn_mfma_f32_16x16x32_bf16(a0, qf0, a, 0, 0, 0);
      a = __builtin_amdgcn_mfma_f32_16x16x32_bf16(a1, qf1, a, 0, 0, 0);
      const float4 mk4 = *(const float4*)&mkb[kv0 + kf * 16 + l4 * 4];
      float4 p;
      p.x = exp2f(fmaf(a[0], c1, fmaf(mk4.x, c2, -C)));
      p.y = exp2f(fmaf(a[1], c1, fmaf(mk4.y, c2, -C)));
      p.z = exp2f(fmaf(a[2], c1, fmaf(mk4.z, c2, -C)));
      p.w = exp2f(fmaf(a[3], c1, fmaf(mk4.w, c2, -C)));
      *(float4*)&awrow[kv0 + kf * 16 + l4 * 4] = p;
      ushort4 pb;
      pb.x = f2bf(p.x); pb.y = f2bf(p.y); pb.z = f2bf(p.z); pb.w = f2bf(p.w);
      const int gby = kf * 32 + l4 * 8;          // byte offset of kvc in 128B row
      *(ushort4*)((char*)PsW + l15 * 128 + (((gby >> 4) ^ (l15 & 7)) * 16) + (gby & 15)) = pb;
    }
    LGKM0();
#pragma unroll
    for (int kk = 0; kk < 2; kk++) {
      const int c = l4 + 4 * kk;
      const v8s pf = *(const v8s*)((const char*)PsW + l15 * 128 + ((c ^ (l15 & 7)) * 16));
#pragma unroll
      for (int nf = 0; nf < 4; nf++) {
        const int hd = nf * 16 + l15;
        const v8s vf = *(const v8s*)&Vtb[vgbase + (size_t)hd * SKV_ + kv0 + kk * 32 + l4 * 8];
        oa[nf] = __builtin_amdgcn_mfma_f32_16x16x32_bf16(pf, vf, oa[nf], 0, 0, 0);
      }
    }
  }

  // ---- X epilogue: transpose oa via Ps, vectorized 16B stores ----
#pragma unroll
  for (int nf = 0; nf < 4; nf++) {
#pragma unroll
    for (int j = 0; j < 4; j++) {
      const int row = l4 * 4 + j;
      const int gby = (nf * 16 + l15) * 2;
      *(unsigned short*)((char*)PsW + row * 128 + (((gby >> 4) ^ (row & 7)) * 16) + (gby & 15)) =
          f2bf(oa[nf][j]);
    }
  }
  LGKM0();
#pragma unroll
  for (int s = 0; s < 2; s++) {
    const int c = l4 + 4 * s;
    const v8s xv = *(const v8s*)((const char*)PsW + l15 * 128 + ((c ^ (l15 & 7)) * 16));
    *(v8s*)&X[((size_t)b * SQ_ + q) * D_ + h * HD_ + c * 8] = xv;
  }
}

extern "C" void kernel_launch(void* const* d_in, const int* in_sizes, int n_in,
                              void* d_out, int out_size, void* d_ws, size_t ws_size,
                              hipStream_t stream) {
  (void)in_sizes; (void)n_in; (void)out_size; (void)ws_size;
  const float* hidden = (const float*)d_in[0];
  const float* enc    = (const float*)d_in[1];
  const float* mask   = (const float*)d_in[2];
  const float* qw     = (const float*)d_in[3];
  const float* qb     = (const float*)d_in[4];
  const float* cw     = (const float*)d_in[5];
  const float* cb     = (const float*)d_in[6];
  const float* pw     = (const float*)d_in[7];
  const float* pb     = (const float*)d_in[8];

  float* out = (float*)d_out;
  float* aw  = out + (size_t)B_ * SQ_ * D_;

  char* ws = (char*)d_ws;
  unsigned short* hbf = (unsigned short*)(ws + (size_t)(0u)  * (1u << 20));  //  8 MB
  unsigned short* ebf = (unsigned short*)(ws + (size_t)(8u)  * (1u << 20));  // 16 MB
  unsigned short* qwt = (unsigned short*)(ws + (size_t)(24u) * (1u << 20));  //  2 MB
  unsigned short* cat = (unsigned short*)(ws + (size_t)(26u) * (1u << 20));  //  4 MB
  unsigned short* cpt = (unsigned short*)(ws + (size_t)(30u) * (1u << 20));  //  2 MB
  unsigned short* Qb  = (unsigned short*)(ws + (size_t)(32u) * (1u << 20));  //  8 MB
  unsigned short* Kb  = (unsigned short*)(ws + (size_t)(40u) * (1u << 20));  // 16 MB
  unsigned short* Vtb = (unsigned short*)(ws + (size_t)(56u) * (1u << 20));  // 16 MB
  unsigned short* Xb  = (unsigned short*)(ws + (size_t)(72u) * (1u << 20));  //  8 MB (total 80 MB)

  hipLaunchKernelGGL(f2bf_k, dim3((B_ * SQ_ * D_ / 4 + 255) / 256), dim3(256), 0, stream,
                     hidden, hbf, B_ * SQ_ * D_ / 4);
  hipLaunchKernelGGL(f2bf_k, dim3((B_ * SKV_ * D_ / 4 + 255) / 256), dim3(256), 0, stream,
                     enc, ebf, B_ * SKV_ * D_ / 4);
  hipLaunchKernelGGL(tconv_k, dim3(D_ / 32, D_ / 32), dim3(32, 8), 0, stream, qw, qwt, D_, D_);
  hipLaunchKernelGGL(tconv_k, dim3(2 * D_ / 32, D_ / 32), dim3(32, 8), 0, stream, cw, cat, D_, 2 * D_);
  hipLaunchKernelGGL(tconv_k, dim3(D_ / 32, D_ / 32), dim3(32, 8), 0, stream, pw, cpt, D_, D_);

  hipLaunchKernelGGL(gemm_bt<0>, dim3(B_ * SQ_ / 128, D_ / 128), dim3(256), 0, stream,
                     hbf, qwt, qb, Qb, (unsigned short*)nullptr, (float*)nullptr, B_ * SQ_, D_, D_);
  hipLaunchKernelGGL(gemm_bt<1>, dim3(B_ * SKV_ / 128, 2 * D_ / 128), dim3(256), 0, stream,
                     ebf, cat, cb, Kb, Vtb, (float*)nullptr, B_ * SKV_, 2 * D_, D_);
  hipLaunchKernelGGL(attn_k, dim3(SQ_ / 64, H_, B_), dim3(256), 0, stream,
                     Qb, Kb, Vtb, mask, aw, Xb);
  hipLaunchKernelGGL(gemm_bt<2>, dim3(B_ * SQ_ / 128, D_ / 128), dim3(256), 0, stream,
                     Xb, cpt, pb, (unsigned short*)nullptr, (unsigned short*)nullptr, out, B_ * SQ_, D_, D_);
}